// Round 1
// baseline (1057.380 us; speedup 1.0000x reference)
//
#include <hip/hip_runtime.h>

// CRF negative log-likelihood, B=128, T=1024, NT=254, N=256.
// One block per batch (256 threads = 4 waves). Thread j owns state j.
// Forward recursion kept in base-2 log space; per-step matvec done in
// exp-space with E=exp(trans) held in per-thread f16 registers, dot via
// v_dot2_f32_f16 (f32 accumulate). One barrier per time step.

typedef _Float16 h16;
typedef __attribute__((ext_vector_type(2))) _Float16 h16x2;
typedef __attribute__((ext_vector_type(8))) _Float16 h16x8;

constexpr int   B_ = 128, T_ = 1024, NT_ = 254, N_ = 256;
constexpr int   START_ = 254, END_ = 255;
constexpr float NEGV = -10000.0f;
constexpr float RLN2 = 1.44269504088896340736f;  // 1/ln2
constexpr float LN2f = 0.69314718055994530942f;

__device__ __forceinline__ float wredmax(float x) {
#pragma unroll
  for (int o = 32; o > 0; o >>= 1) x = fmaxf(x, __shfl_xor(x, o, 64));
  return x;
}
__device__ __forceinline__ float wredsum(float x) {
#pragma unroll
  for (int o = 32; o > 0; o >>= 1) x += __shfl_xor(x, o, 64);
  return x;
}

__global__ __launch_bounds__(256, 1) void crf_fwd(
    const float* __restrict__ unary, const int* __restrict__ tags,
    const int* __restrict__ lengths, const float* __restrict__ trans,
    float* __restrict__ out)
{
  const int b    = blockIdx.x;
  const int j    = threadIdx.x;      // state index 0..255
  const int lane = j & 63;
  const int wid  = j >> 6;
  const int len  = lengths[b];       // 1..T

  __shared__ alignas(16) h16   s16[2][N_];   // exp-space state, double-buffered
  __shared__ alignas(16) float wmax[2][4];   // per-wave maxes, double-buffered
  __shared__ float red[12];                  // final reductions

  // ---- E row j = exp(trans[j, :]) into 128 packed-f16 registers ----
  h16x2 e[128];
  {
    const float4* tr4 = reinterpret_cast<const float4*>(trans + (size_t)j * N_);
#pragma unroll
    for (int c = 0; c < 64; ++c) {
      float4 t4 = tr4[c];
      h16x2 a, bb;
      a.x  = (h16)__expf(t4.x); a.y  = (h16)__expf(t4.y);
      bb.x = (h16)__expf(t4.z); bb.y = (h16)__expf(t4.w);
      e[2 * c] = a; e[2 * c + 1] = bb;
    }
  }
  const float te2 = trans[END_ * N_ + j] * RLN2;   // trans[end, j] / ln2

  const float* ub = unary + (size_t)b * T_ * NT_;

  // ---- gold-path partial: thread handles t = j, j+256, j+512, j+768 ----
  float gold = 0.f;
#pragma unroll
  for (int q = 0; q < 4; ++q) {
    int t = j + q * 256;
    if (t < len) {
      int curr = tags[b * T_ + t];
      int prev = (t == 0) ? START_ : tags[b * T_ + t - 1];
      gold += trans[curr * N_ + prev] + ub[(size_t)t * NT_ + curr];
    }
  }

  // ---- init: alpha0 = NEG except start state; a2 = alpha/ln2 ----
  float a2 = (j == START_) ? 0.f : NEGV * RLN2;
  float Ms = 0.f;                      // normalizer embedded in current s buffer
  s16[0][j] = (h16)((j == START_) ? 1.f : 0.f);
  {
    float wm = wredmax(a2);
    if (lane == 0) wmax[0][wid] = wm;
  }

  // unary prefetch, depth 2
  float uA = (j < NT_) ? ub[j] : NEGV;                 // t = 0 (len >= 1)
  float uB = (j < NT_) ? ub[NT_ + j] : NEGV;           // t = 1

  for (int t = 0; t < len; ++t) {
    const int cur = t & 1, nxt = cur ^ 1;
    float uN = NEGV;
    if (j < NT_ && t + 2 < T_) uN = ub[(size_t)(t + 2) * NT_ + j];

    __syncthreads();  // publishes s16[cur], wmax[cur]

    float4 wm4 = *reinterpret_cast<const float4*>(wmax[cur]);
    float  M   = fmaxf(fmaxf(wm4.x, wm4.y), fmaxf(wm4.z, wm4.w)); // exact max(a2)

    // v[j] = sum_k E[j,k] * s[k]  (128 x v_dot2_f32_f16, 4 accumulators)
    const h16x8* sp = reinterpret_cast<const h16x8*>(s16[cur]);
    float v0 = 0.f, v1 = 0.f, v2 = 0.f, v3 = 0.f;
#pragma unroll
    for (int c = 0; c < 32; ++c) {
      union { h16x8 v; h16x2 h[4]; } u8;
      u8.v = sp[c];
      v0 = __builtin_amdgcn_fdot2(e[4 * c + 0], u8.h[0], v0, false);
      v1 = __builtin_amdgcn_fdot2(e[4 * c + 1], u8.h[1], v1, false);
      v2 = __builtin_amdgcn_fdot2(e[4 * c + 2], u8.h[2], v2, false);
      v3 = __builtin_amdgcn_fdot2(e[4 * c + 3], u8.h[3], v3, false);
    }
    float v = (v0 + v1) + (v2 + v3);

    // a2' = u/ln2 + Ms + log2(v);  s' = exp2(a2' - (M+4))  [f16-safe: <= 2^12.8]
    float a2n = uA * RLN2 + Ms + __log2f(v);
    float Mh  = M + 4.0f;
    s16[nxt][j] = (h16)__builtin_exp2f(a2n - Mh);
    float wm = wredmax(a2n);
    if (lane == 0) wmax[nxt][wid] = wm;

    a2 = a2n; Ms = Mh;
    uA = uB;  uB = uN;
  }

  // ---- fwd = ln2 * log2sumexp2_j(a2 + trans[end,j]/ln2); out = fwd - gold ----
  __syncthreads();
  float x   = a2 + te2;
  float wmx = wredmax(x);
  if (lane == 0) red[wid] = wmx;
  __syncthreads();
  float Mx = fmaxf(fmaxf(red[0], red[1]), fmaxf(red[2], red[3]));
  float ex = __builtin_exp2f(x - Mx);
  float sx = wredsum(ex);
  float sg = wredsum(gold);
  if (lane == 0) { red[4 + wid] = sx; red[8 + wid] = sg; }
  __syncthreads();
  if (j == 0) {
    float S = (red[4] + red[5]) + (red[6] + red[7]);
    float G = (red[8] + red[9]) + (red[10] + red[11]);
    float fwd = LN2f * (Mx + __log2f(S));
    int last = tags[b * T_ + (len - 1)];
    G += trans[END_ * N_ + last];
    out[b] = fwd - G;
  }
}

extern "C" void kernel_launch(void* const* d_in, const int* in_sizes, int n_in,
                              void* d_out, int out_size, void* d_ws, size_t ws_size,
                              hipStream_t stream) {
  const float* unary   = (const float*)d_in[0];
  const int*   tags    = (const int*)d_in[1];
  const int*   lengths = (const int*)d_in[2];
  const float* trans   = (const float*)d_in[3];
  float*       out     = (float*)d_out;
  hipLaunchKernelGGL(crf_fwd, dim3(B_), dim3(256), 0, stream,
                     unary, tags, lengths, trans, out);
}

// Round 2
// 977.618 us; speedup vs baseline: 1.0816x; 1.0816x over previous
//
#include <hip/hip_runtime.h>

// CRF negative log-likelihood, B=128, T=1024, NT=254, N=256.
// One block per batch (256 threads = 4 waves). Thread j owns state j.
// Fully linear-space recursion: s' = (E·s) * 2^(u/ln2) / (16*r), with the
// normalizer exponent tracked in Ms (Ms += 4 + log2(r)). r = max of the
// previous s-buffer (one-step lag), computed via DPP wave-max + LDS.
// Raw s_barrier (lgkmcnt only) so unary prefetches stay in flight.

typedef _Float16 h16;
typedef __attribute__((ext_vector_type(2))) _Float16 h16x2;
typedef __attribute__((ext_vector_type(8))) _Float16 h16x8;

constexpr int   B_ = 128, T_ = 1024, NT_ = 254, N_ = 256;
constexpr int   START_ = 254, END_ = 255;
constexpr float NEGV = -10000.0f;
constexpr float RLN2 = 1.44269504088896340736f;  // 1/ln2
constexpr float LN2f = 0.69314718055994530942f;

// barrier that does NOT drain vmcnt: LDS-ordered only.
#define WG_BARRIER() asm volatile("s_waitcnt lgkmcnt(0)\n\ts_barrier" ::: "memory")

__device__ __forceinline__ float wredsum(float x) {
#pragma unroll
  for (int o = 32; o > 0; o >>= 1) x += __shfl_xor(x, o, 64);
  return x;
}

// Wave max via DPP; result valid in lane 63. rocPRIM-style sequence.
__device__ __forceinline__ float dpp_wavemax(float x) {
  float t;
#define DPPSTEP(ctrl)                                                          \
  t = __builtin_bit_cast(float,                                                \
        __builtin_amdgcn_update_dpp(__builtin_bit_cast(int, x),                \
                                    __builtin_bit_cast(int, x),                \
                                    ctrl, 0xF, 0xF, false));                   \
  x = fmaxf(x, t);
  DPPSTEP(0x111)  // row_shr:1
  DPPSTEP(0x112)  // row_shr:2
  DPPSTEP(0x114)  // row_shr:4
  DPPSTEP(0x118)  // row_shr:8
  DPPSTEP(0x142)  // row_bcast:15
  DPPSTEP(0x143)  // row_bcast:31
#undef DPPSTEP
  return x;  // lane 63 holds the wave max
}

__global__ __launch_bounds__(256, 1) void crf_fwd(
    const float* __restrict__ unary, const int* __restrict__ tags,
    const int* __restrict__ lengths, const float* __restrict__ trans,
    float* __restrict__ out)
{
  const int b    = blockIdx.x;
  const int j    = threadIdx.x;      // state index 0..255
  const int lane = j & 63;
  const int wid  = j >> 6;
  const int len  = lengths[b];       // 1..T

  __shared__ alignas(16) h16   s16[2][N_];   // exp-space state, double-buffered
  __shared__ alignas(16) float wmax[2][4];   // per-wave max of s-buffer
  __shared__ float red[8];                   // final reductions

  // ---- E row j = exp(trans[j, :]) into 128 packed-f16 registers ----
  h16x2 e[128];
  {
    const float4* tr4 = reinterpret_cast<const float4*>(trans + (size_t)j * N_);
#pragma unroll
    for (int c = 0; c < 64; ++c) {
      float4 t4 = tr4[c];
      h16x2 a, bb;
      a.x  = (h16)__expf(t4.x); a.y  = (h16)__expf(t4.y);
      bb.x = (h16)__expf(t4.z); bb.y = (h16)__expf(t4.w);
      e[2 * c] = a; e[2 * c + 1] = bb;
    }
  }
  const float te2 = trans[END_ * N_ + j] * RLN2;   // trans[end, j] / ln2

  const float* ub = unary + (size_t)b * T_ * NT_;

  // ---- gold-path partial: thread handles t = j, j+256, j+512, j+768 ----
  float gold = 0.f;
#pragma unroll
  for (int q = 0; q < 4; ++q) {
    int t = j + q * 256;
    if (t < len) {
      int curr = tags[b * T_ + t];
      int prev = (t == 0) ? START_ : tags[b * T_ + t - 1];
      gold += trans[curr * N_ + prev] + ub[(size_t)t * NT_ + curr];
    }
  }

  // ---- init: s0 = 1 at START, else 0 (normalizer exponent Ms = 0) ----
  float sj = (j == START_) ? 1.f : 0.f;
  s16[0][j] = (h16)sj;
  {
    float wm0 = dpp_wavemax(sj);
    if (lane == 63) wmax[0][wid] = wm0;
  }
  float Ms   = 0.f;
  float sfin = sj;

  // unary prefetch, depth 2
  float uA = (j < NT_) ? ub[j] : NEGV;                 // t = 0
  float uB = (j < NT_) ? ub[NT_ + j] : NEGV;           // t = 1

  for (int t = 0; t < len; ++t) {
    const int cur = t & 1, nxt = cur ^ 1;

    // eu from a 2-step-old load: vmcnt wait is free here
    float eu = __builtin_exp2f(uA * RLN2);

    // issue prefetch for t+2; stays in flight across the raw barrier
    float uN = NEGV;
    if (j < NT_ && t + 2 < T_) uN = ub[(size_t)(t + 2) * NT_ + j];

    WG_BARRIER();  // publishes s16[cur], wmax[cur]; does NOT drain vmcnt

    // r = max of current s-buffer (exact, from previous step's DPP maxes)
    float4 wm4 = *reinterpret_cast<const float4*>(wmax[cur]);

    // v[j] = sum_k E[j,k] * s[k]  (128 x v_dot2_f32_f16, 4 accumulators)
    const h16x8* sp = reinterpret_cast<const h16x8*>(s16[cur]);
    float v0 = 0.f, v1 = 0.f, v2 = 0.f, v3 = 0.f;
#pragma unroll
    for (int c = 0; c < 32; ++c) {
      union { h16x8 v; h16x2 h[4]; } u8;
      u8.v = sp[c];
      v0 = __builtin_amdgcn_fdot2(e[4 * c + 0], u8.h[0], v0, false);
      v1 = __builtin_amdgcn_fdot2(e[4 * c + 1], u8.h[1], v1, false);
      v2 = __builtin_amdgcn_fdot2(e[4 * c + 2], u8.h[2], v2, false);
      v3 = __builtin_amdgcn_fdot2(e[4 * c + 3], u8.h[3], v3, false);
    }
    float v = (v0 + v1) + (v2 + v3);

    // these all overlap with the dot (r available early):
    float r     = fmaxf(fmaxf(wm4.x, wm4.y), fmaxf(wm4.z, wm4.w));
    float scale = 0.0625f / r;           // 1/(16 r), precise divide
    Ms += 4.0f + __log2f(r);             // bookkeeping chain, off critical path

    float w   = v * eu;                  // = exp2(a2' - Ms_old), unnormalized
    float sn  = w * scale;               // new s, bounded <= 2^13
    sfin      = sn;
    s16[nxt][j] = (h16)sn;

    float wm = dpp_wavemax(w);           // ~12 VALU ops
    if (lane == 63) wmax[nxt][wid] = wm * scale;   // wave max of s'

    uA = uB; uB = uN;
  }

  // ---- fwd = ln2*(Ms + log2(sum_j sfin_j * 2^te2_j)); out = fwd - gold ----
  float p = sfin * __builtin_exp2f(te2);
  float S = wredsum(p);
  float G = wredsum(gold);
  if (lane == 0) { red[wid] = S; red[4 + wid] = G; }
  __syncthreads();
  if (j == 0) {
    float Ssum = (red[0] + red[1]) + (red[2] + red[3]);
    float Gsum = (red[4] + red[5]) + (red[6] + red[7]);
    float fwd  = LN2f * (Ms + __log2f(Ssum));
    int last = tags[b * T_ + (len - 1)];
    Gsum += trans[END_ * N_ + last];
    out[b] = fwd - Gsum;
  }
}

extern "C" void kernel_launch(void* const* d_in, const int* in_sizes, int n_in,
                              void* d_out, int out_size, void* d_ws, size_t ws_size,
                              hipStream_t stream) {
  const float* unary   = (const float*)d_in[0];
  const int*   tags    = (const int*)d_in[1];
  const int*   lengths = (const int*)d_in[2];
  const float* trans   = (const float*)d_in[3];
  float*       out     = (float*)d_out;
  hipLaunchKernelGGL(crf_fwd, dim3(B_), dim3(256), 0, stream,
                     unary, tags, lengths, trans, out);
}